// Round 6
// baseline (95.624 us; speedup 1.0000x reference)
//
#include <hip/hip_runtime.h>
#include <math.h>

#define NCLS 81
#define KMAX 200
#define NMAX 1536      // fused path supports N <= 1536 (N=1500)
#define WCAP 256       // per-wave compacted candidate capacity
#define NWAVE 16
#define SORT_CAP 2048

// ===========================================================================
// FUSED kernel: one block per batch (1024 threads = 16 waves).
//   Phase 1: per-row 81-wide argmax (prob>0.7 => unique strict argmax =>
//            candidate; class 0 can never pass), decode box, all into LDS.
//   Phase 2: per-class greedy NMS, one class per wave round-robin; candidate
//            rows are disjoint across classes so waves need no block sync.
//   Phase 3: bitonic top-200 on (score desc, flat-index asc) keys.
// Nothing but the final output ever touches global memory.
// ===========================================================================
__global__ __launch_bounds__(1024) void decoder_fused(
    const float* __restrict__ rois,     // [B*N,4]
    const float* __restrict__ deltas,   // [B*N,81*4]
    const float* __restrict__ probs,    // [B*N,81]
    float* __restrict__ out, int N, int B) {
  const int b    = blockIdx.x;
  const int tid  = threadIdx.x;
  const int lane = tid & 63;
  const int wv   = tid >> 6;

  __shared__ int    s_cls[NMAX];          // candidate class or -1
  __shared__ float  s_sc[NMAX];           // row max prob
  __shared__ float4 s_box[NMAX];          // decoded (unclipped) box
  __shared__ int    s_widx[NWAVE * WCAP]; // per-wave compacted row indices
  __shared__ float  s_wsc[NWAVE * WCAP];  // per-wave mutable scores
  __shared__ unsigned long long s_key[SORT_CAP];
  __shared__ int    s_pay[SORT_CAP];      // key slot -> obox slot
  __shared__ float4 s_obox[NMAX];         // clipped boxes of selections
  __shared__ int    s_outcnt;

  if (tid == 0) s_outcnt = 0;

  // -------- Phase 1: row scan --------
  for (int q = 0; q < 2; ++q) {
    const int s = tid + q * 1024;
    if (s >= NMAX) break;
    if (s < N) {
      const int row = b * N + s;
      const float* pr = probs + (size_t)row * NCLS;
      const float4* p4 = (const float4*)pr;   // row base: row*324*4B, 16B-aligned
      float mv = pr[0];
      int arg = 0;
#pragma unroll
      for (int j = 0; j < 20; ++j) {          // k = 0..79, all loads in flight
        const float4 v = p4[j];
        const int k0 = j * 4;
        if (v.x > mv) { mv = v.x; arg = k0; }
        if (v.y > mv) { mv = v.y; arg = k0 + 1; }
        if (v.z > mv) { mv = v.z; arg = k0 + 2; }
        if (v.w > mv) { mv = v.w; arg = k0 + 3; }
      }
      const float v80 = pr[80];
      if (v80 > mv) { mv = v80; arg = 80; }   // strict > keeps lowest idx
      const bool cand = (mv > 0.7f) && (arg != 0);
      s_cls[s] = cand ? arg : -1;
      s_sc[s]  = mv;
      if (cand) {
        const float4 r4 = *(const float4*)(rois + (size_t)row * 4);
        const float h = r4.z - r4.x, w = r4.w - r4.y;
        const float cy = r4.x + 0.5f * h, cx = r4.y + 0.5f * w;
        const float4 d4 = *(const float4*)(deltas + (size_t)row * (NCLS * 4) + arg * 4);
        const float bh  = expf(d4.z * 0.2f) * h;
        const float bw  = expf(d4.w * 0.2f) * w;
        const float bcy = d4.x * 0.1f * h + cy;
        const float bcx = d4.y * 0.1f * w + cx;
        const float y1 = bcy - 0.5f * bh, x1 = bcx - 0.5f * bw;
        s_box[s] = make_float4(y1, x1, y1 + bh, x1 + bw);   // unclipped for NMS
      }
    } else {
      s_cls[s] = -1;   // pad so compaction can scan a 64-multiple range
    }
  }
  __syncthreads();

  // -------- Phase 2: per-class NMS (wave-independent; disjoint rows) --------
  const int iters = (N + 63) >> 6;
  int*   widx = s_widx + wv * WCAP;
  float* wsc  = s_wsc + wv * WCAP;

  for (int l = wv; l < NCLS; l += NWAVE) {
    if (l == 0) continue;
    // compaction (row-ascending order preserved)
    int m = 0;
    for (int it = 0; it < iters; ++it) {
      const int idx = (it << 6) + lane;
      const bool cand = (s_cls[idx] == l);
      const unsigned long long mask = __ballot(cand);
      if (cand) {
        const int p = m + __popcll(mask & ((1ull << lane) - 1ull));
        if (p < WCAP) widx[p] = idx;
      }
      m += __popcll(mask);
    }
    if (m == 0) continue;
    __builtin_amdgcn_wave_barrier();

    if (m <= WCAP) {
      for (int i = lane; i < m; i += 64) wsc[i] = s_sc[widx[i]];
      int kept = 0;
      while (kept < KMAX) {
        __builtin_amdgcn_wave_barrier();
        float best = -1.0f; int bi = -1;
        for (int i = lane; i < m; i += 64) {
          const float s = wsc[i];
          if (s > best) { best = s; bi = i; }   // ascending: first max kept
        }
        for (int off = 32; off > 0; off >>= 1) {
          const float ob = __shfl_down(best, off);
          const int   oi = __shfl_down(bi, off);
          if (ob > best || (ob == best && (unsigned)oi < (unsigned)bi)) {
            best = ob; bi = oi;
          }
        }
        best = __shfl(best, 0);
        bi   = __shfl(bi, 0);
        if (best <= 0.7f) break;
        const float4 bb = s_box[widx[bi]];
        const float a1 = (bb.z - bb.x) * (bb.w - bb.y);
        for (int i = lane; i < m; i += 64) {
          const float4 tb = s_box[widx[i]];
          const float yy1 = fmaxf(bb.x, tb.x), xx1 = fmaxf(bb.y, tb.y);
          const float yy2 = fminf(bb.z, tb.z), xx2 = fminf(bb.w, tb.w);
          const float inter = fmaxf(yy2 - yy1, 0.0f) * fmaxf(xx2 - xx1, 0.0f);
          const float a2  = (tb.z - tb.x) * (tb.w - tb.y);
          const float uni = a1 + a2 - inter;
          const float iou = (uni > 0.0f) ? (inter / uni) : 0.0f;
          if (iou > 0.5f) wsc[i] = -INFINITY;   // self iou=1 -> suppressed
        }
        if (lane == 0) {
          const int slot = atomicAdd(&s_outcnt, 1);
          const unsigned fi = (unsigned)(l * KMAX + kept);
          s_key[slot] = ((unsigned long long)__float_as_uint(best) << 32) |
                        (unsigned long long)(0xFFFFFFFFu - fi);
          s_pay[slot] = slot;
          s_obox[slot] = make_float4(
              fminf(fmaxf(bb.x, 0.0f), 1.0f), fminf(fmaxf(bb.y, 0.0f), 1.0f),
              fminf(fmaxf(bb.z, 0.0f), 1.0f), fminf(fmaxf(bb.w, 0.0f), 1.0f));
        }
        kept++;
      }
    } else {
      // rare fallback: NMS over the full arrays with class predicate
      int kept = 0;
      while (kept < KMAX) {
        __builtin_amdgcn_wave_barrier();
        float best = -1.0f; int bi = -1;
        for (int it = 0; it < iters; ++it) {
          const int idx = (it << 6) + lane;
          const float s = (s_cls[idx] == l) ? s_sc[idx] : -INFINITY;
          if (s > best) { best = s; bi = idx; }
        }
        for (int off = 32; off > 0; off >>= 1) {
          const float ob = __shfl_down(best, off);
          const int   oi = __shfl_down(bi, off);
          if (ob > best || (ob == best && (unsigned)oi < (unsigned)bi)) {
            best = ob; bi = oi;
          }
        }
        best = __shfl(best, 0);
        bi   = __shfl(bi, 0);
        if (best <= 0.7f) break;
        const float4 bb = s_box[bi];
        const float a1 = (bb.z - bb.x) * (bb.w - bb.y);
        for (int it = 0; it < iters; ++it) {
          const int idx = (it << 6) + lane;
          if (s_cls[idx] == l) {
            const float4 tb = s_box[idx];
            const float yy1 = fmaxf(bb.x, tb.x), xx1 = fmaxf(bb.y, tb.y);
            const float yy2 = fminf(bb.z, tb.z), xx2 = fminf(bb.w, tb.w);
            const float inter = fmaxf(yy2 - yy1, 0.0f) * fmaxf(xx2 - xx1, 0.0f);
            const float a2  = (tb.z - tb.x) * (tb.w - tb.y);
            const float uni = a1 + a2 - inter;
            const float iou = (uni > 0.0f) ? (inter / uni) : 0.0f;
            if (iou > 0.5f) s_sc[idx] = -INFINITY;  // class-l rows only: disjoint
          }
        }
        if (lane == 0) {
          const int slot = atomicAdd(&s_outcnt, 1);
          const unsigned fi = (unsigned)(l * KMAX + kept);
          s_key[slot] = ((unsigned long long)__float_as_uint(best) << 32) |
                        (unsigned long long)(0xFFFFFFFFu - fi);
          s_pay[slot] = slot;
          s_obox[slot] = make_float4(
              fminf(fmaxf(bb.x, 0.0f), 1.0f), fminf(fmaxf(bb.y, 0.0f), 1.0f),
              fminf(fmaxf(bb.z, 0.0f), 1.0f), fminf(fmaxf(bb.w, 0.0f), 1.0f));
        }
        kept++;
      }
    }
  }
  __syncthreads();

  // -------- Phase 3: bitonic top-200 --------
  const int cnt = s_outcnt;                 // <= N <= NMAX <= SORT_CAP
  int M = 64;
  while (M < cnt) M <<= 1;
  for (int i = tid; i < M; i += 1024)
    if (i >= cnt) s_key[i] = 0ull;
  __syncthreads();

  for (int kk = 2; kk <= M; kk <<= 1) {
    for (int j2 = kk >> 1; j2 > 0; j2 >>= 1) {
      for (int i = tid; i < M; i += 1024) {
        const int ixj = i ^ j2;
        if (ixj > i) {
          const bool up = ((i & kk) == 0);  // descending overall
          const unsigned long long a = s_key[i], bb2 = s_key[ixj];
          const bool sw = up ? (a < bb2) : (a > bb2);
          if (sw) {
            s_key[i] = bb2; s_key[ixj] = a;
            const int t = s_pay[i]; s_pay[i] = s_pay[ixj]; s_pay[ixj] = t;
          }
        }
      }
      __syncthreads();
    }
  }

  if (tid < KMAX) {
    float sc = 0.0f, lb = 0.0f;
    float4 bx = make_float4(0.0f, 0.0f, 0.0f, 0.0f);
    if (tid < cnt) {
      const unsigned long long k = s_key[tid];
      sc = __uint_as_float((unsigned)(k >> 32));
      const unsigned fi = 0xFFFFFFFFu - (unsigned)(k & 0xFFFFFFFFull);
      lb = (float)(fi / KMAX);
      bx = s_obox[s_pay[tid]];
    }
    float* ob = out + (size_t)b * (KMAX * 4) + (size_t)tid * 4;
    ob[0] = bx.x; ob[1] = bx.y; ob[2] = bx.z; ob[3] = bx.w;
    const size_t boxes_sz = (size_t)B * KMAX * 4;
    out[boxes_sz + (size_t)b * KMAX + tid] = lb;
    out[boxes_sz + (size_t)B * KMAX + (size_t)b * KMAX + tid] = sc;
  }
}

// ===========================================================================
// Fallback path for N > NMAX: the verified R5 three-kernel pipeline.
// ===========================================================================
__global__ __launch_bounds__(64) void row_scan_rt(
    const float* __restrict__ rois, const float* __restrict__ deltas,
    const float* __restrict__ probs, int* __restrict__ cand_cls,
    float* __restrict__ cand_sc, float4* __restrict__ cand_box, int BN) {
  __shared__ float s_p[64 * NCLS];
  const int lane = threadIdx.x;
  const int row0 = blockIdx.x * 64;
  const int tot = (min(64, BN - row0)) * NCLS;
  const float* src = probs + (size_t)row0 * NCLS;
  for (int i = lane; i < tot; i += 64) s_p[i] = src[i];
  __syncthreads();
  const int row = row0 + lane;
  if (row >= BN) return;
  const float* pr = s_p + lane * NCLS;
  float maxv = pr[0];
  int arg = 0;
  for (int k = 1; k < NCLS; ++k) {
    const float v = pr[k];
    if (v > maxv) { maxv = v; arg = k; }
  }
  const bool cand = (maxv > 0.7f) && (arg != 0);
  cand_cls[row] = cand ? arg : -1;
  cand_sc[row] = maxv;
  if (cand) {
    const float4 r4 = *(const float4*)(rois + (size_t)row * 4);
    const float h = r4.z - r4.x, w = r4.w - r4.y;
    const float cy = r4.x + 0.5f * h, cx = r4.y + 0.5f * w;
    const float4 d4 = *(const float4*)(deltas + (size_t)row * (NCLS * 4) + arg * 4);
    const float bh  = expf(d4.z * 0.2f) * h;
    const float bw  = expf(d4.w * 0.2f) * w;
    const float bcy = d4.x * 0.1f * h + cy;
    const float bcx = d4.y * 0.1f * w + cx;
    const float y1 = bcy - 0.5f * bh, x1 = bcx - 0.5f * bw;
    cand_box[row] = make_float4(y1, x1, y1 + bh, x1 + bw);
  }
}

__global__ __launch_bounds__(64) void nms_per_class_rt(
    const int* __restrict__ cand_cls, const float* __restrict__ cand_sc,
    const float4* __restrict__ cand_box, float* __restrict__ entries,
    int* __restrict__ counts, int N) {
  const int bl = blockIdx.x;
  const int b  = bl / NCLS;
  const int l  = bl % NCLS;
  const int lane = threadIdx.x;
  if (l == 0) { if (lane == 0) counts[bl] = 0; return; }

  __shared__ int   s_idx[8192];
  __shared__ float s_score[8192];
  __shared__ int   s_sel[KMAX];
  __shared__ float s_sel_score[KMAX];

  int m = 0;
  for (int n0 = 0; n0 < N; n0 += 64) {
    const int n = n0 + lane;
    const bool cand = (n < N) && (cand_cls[b * N + n] == l);
    const unsigned long long mask = __ballot(cand);
    if (cand) s_idx[m + __popcll(mask & ((1ull << lane) - 1ull))] = n;
    m += __popcll(mask);
  }
  __syncthreads();
  for (int i = lane; i < m; i += 64) s_score[i] = cand_sc[b * N + s_idx[i]];
  __syncthreads();

  int kept = 0;
  while (kept < KMAX) {
    float best = -1.0f; int bi = -1;
    for (int i = lane; i < m; i += 64) {
      const float s = s_score[i];
      if (s > best) { best = s; bi = i; }
    }
    for (int off = 32; off > 0; off >>= 1) {
      const float ob = __shfl_down(best, off);
      const int   oi = __shfl_down(bi, off);
      if (ob > best || (ob == best && (unsigned)oi < (unsigned)bi)) { best = ob; bi = oi; }
    }
    best = __shfl(best, 0); bi = __shfl(bi, 0);
    if (best <= 0.7f) break;
    if (lane == 0) { s_sel[kept] = bi; s_sel_score[kept] = best; }
    const float4 bb = cand_box[b * N + s_idx[bi]];
    const float a1 = (bb.z - bb.x) * (bb.w - bb.y);
    for (int i = lane; i < m; i += 64) {
      const float4 tb = cand_box[b * N + s_idx[i]];
      const float yy1 = fmaxf(bb.x, tb.x), xx1 = fmaxf(bb.y, tb.y);
      const float yy2 = fminf(bb.z, tb.z), xx2 = fminf(bb.w, tb.w);
      const float inter = fmaxf(yy2 - yy1, 0.0f) * fmaxf(xx2 - xx1, 0.0f);
      const float a2  = (tb.z - tb.x) * (tb.w - tb.y);
      const float uni = a1 + a2 - inter;
      const float iou = (uni > 0.0f) ? (inter / uni) : 0.0f;
      if (iou > 0.5f) s_score[i] = -INFINITY;
    }
    kept++;
    __syncthreads();
  }
  __syncthreads();

  if (lane == 0) counts[bl] = kept;
  float* ebase = entries + (size_t)bl * KMAX * 8;
  for (int i = lane; i < kept; i += 64) {
    float* e = ebase + (size_t)i * 8;
    const float4 bb = cand_box[b * N + s_idx[s_sel[i]]];
    e[0] = s_sel_score[i];
    e[1] = fminf(fmaxf(bb.x, 0.0f), 1.0f);
    e[2] = fminf(fmaxf(bb.y, 0.0f), 1.0f);
    e[3] = fminf(fmaxf(bb.z, 0.0f), 1.0f);
    e[4] = fminf(fmaxf(bb.w, 0.0f), 1.0f);
  }
}

__global__ __launch_bounds__(1024) void topk_per_batch(
    const float* __restrict__ entries, const int* __restrict__ counts,
    float* __restrict__ out, int B) {
  const int b   = blockIdx.x;
  const int tid = threadIdx.x;
  __shared__ int s_cnt[NCLS];
  __shared__ int s_off[NCLS];
  __shared__ int s_total, s_M;
  __shared__ unsigned long long s_key[SORT_CAP];

  if (tid < NCLS) s_cnt[tid] = counts[b * NCLS + tid];
  __syncthreads();
  if (tid == 0) {
    int acc = 0;
    for (int l = 0; l < NCLS; ++l) { s_off[l] = acc; acc += s_cnt[l]; }
    s_total = acc;
    int M = 64;
    while (M < acc) M <<= 1;
    s_M = M;
  }
  __syncthreads();
  const int c = s_total;
  const int M = s_M;
  for (int i = tid; i < M; i += 1024) s_key[i] = 0ull;
  __syncthreads();
  for (int j = tid; j < NCLS * KMAX; j += 1024) {
    const int l = j / KMAX, k = j - l * KMAX;
    if (k < s_cnt[l]) {
      const float sc = entries[((size_t)(b * NCLS + l) * KMAX + k) * 8];
      s_key[s_off[l] + k] =
          ((unsigned long long)__float_as_uint(sc) << 32) |
          (unsigned long long)(0xFFFFFFFFu - (unsigned)(l * KMAX + k));
    }
  }
  __syncthreads();
  for (int kk = 2; kk <= M; kk <<= 1) {
    for (int j2 = kk >> 1; j2 > 0; j2 >>= 1) {
      for (int i = tid; i < M; i += 1024) {
        const int ixj = i ^ j2;
        if (ixj > i) {
          const bool up = ((i & kk) == 0);
          const unsigned long long a = s_key[i], bb = s_key[ixj];
          const bool sw = up ? (a < bb) : (a > bb);
          if (sw) { s_key[i] = bb; s_key[ixj] = a; }
        }
      }
      __syncthreads();
    }
  }
  if (tid < KMAX) {
    float sc = 0.0f, lb = 0.0f, b0 = 0.0f, b1 = 0.0f, b2 = 0.0f, b3 = 0.0f;
    if (tid < c) {
      const unsigned long long k = s_key[tid];
      const unsigned fi = 0xFFFFFFFFu - (unsigned)(k & 0xFFFFFFFFull);
      const int l = fi / KMAX, kk2 = fi - l * KMAX;
      const float* e = entries + ((size_t)(b * NCLS + l) * KMAX + kk2) * 8;
      sc = e[0]; lb = (float)l;
      b0 = e[1]; b1 = e[2]; b2 = e[3]; b3 = e[4];
    }
    float* ob = out + (size_t)b * (KMAX * 4) + (size_t)tid * 4;
    ob[0] = b0; ob[1] = b1; ob[2] = b2; ob[3] = b3;
    const size_t boxes_sz = (size_t)B * KMAX * 4;
    out[boxes_sz + (size_t)b * KMAX + tid] = lb;
    out[boxes_sz + (size_t)B * KMAX + (size_t)b * KMAX + tid] = sc;
  }
}

// ---------------------------------------------------------------------------
extern "C" void kernel_launch(void* const* d_in, const int* in_sizes, int n_in,
                              void* d_out, int out_size, void* d_ws, size_t ws_size,
                              hipStream_t stream) {
  const float* rois   = (const float*)d_in[0];
  const float* deltas = (const float*)d_in[1];
  const float* probs  = (const float*)d_in[2];
  float* out = (float*)d_out;

  const int B = 4;
  const int N = in_sizes[0] / (B * 4);   // 1500

  if (N <= NMAX) {
    hipLaunchKernelGGL(decoder_fused, dim3(B), dim3(1024), 0, stream,
                       rois, deltas, probs, out, N, B);
  } else {
    char* ws = (char*)d_ws;
    int*    counts   = (int*)ws;
    float*  entries  = (float*)(ws + 4096);
    int*    cand_cls = (int*)(ws + 4096 + 2100000);
    float*  cand_sc  = (float*)(ws + 4096 + 2100000 + 64 * (size_t)N);
    float4* cand_box = (float4*)(ws + 4096 + 2100000 + 128 * (size_t)N);
    const int BN = B * N;
    hipLaunchKernelGGL(row_scan_rt, dim3((BN + 63) / 64), dim3(64), 0, stream,
                       rois, deltas, probs, cand_cls, cand_sc, cand_box, BN);
    hipLaunchKernelGGL(nms_per_class_rt, dim3(B * NCLS), dim3(64), 0, stream,
                       cand_cls, cand_sc, cand_box, entries, counts, N);
    hipLaunchKernelGGL(topk_per_batch, dim3(B), dim3(1024), 0, stream,
                       entries, counts, out, B);
  }
}

// Round 7
// 87.000 us; speedup vs baseline: 1.0991x; 1.0991x over previous
//
#include <hip/hip_runtime.h>
#include <math.h>

#define NCLS 81
#define KMAX 200
#define NMAX 1536      // per-class candidate cap, template path (>= N=1500)
#define FCAP 2048      // per-batch flat selection list capacity (>= N)

// ws layout:
//   counters [8] int           @ 0
//   flat     [B][FCAP][8] f32  @ 256       (4*2048*32B = 256 KB)
//   cand_cls [B*N] int         @ 262400
//   cand_sc  [B*N] float       @ +24064
//   cand_box [B*N] float4      @ +24064

// ---------------------------------------------------------------------------
// K1: one wave per 64 rows. Two-phase staging (global->reg burst, reg->LDS),
// per-lane 81-wide argmax (prob>0.7 => unique strict argmax => candidate;
// class 0 can never pass), decode box, dense outputs. Block 0 zeroes counters.
// ---------------------------------------------------------------------------
template <int NT>
__global__ __launch_bounds__(64) void row_scan(
    const float* __restrict__ rois,     // [B*NT,4]
    const float* __restrict__ deltas,   // [B*NT,81*4]
    const float* __restrict__ probs,    // [B*NT,81]
    int* __restrict__ cand_cls,         // [B*NT]
    float* __restrict__ cand_sc,        // [B*NT]
    float4* __restrict__ cand_box,      // [B*NT]
    int* __restrict__ counters,         // [8]
    int BN) {
  constexpr int NV4 = (64 * NCLS) / 4;  // 1296 float4 per 64-row tile
  __shared__ float s_p[64 * NCLS];
  const int lane = threadIdx.x;
  const int row0 = blockIdx.x * 64;

  if (blockIdx.x == 0 && lane < 8) counters[lane] = 0;

  if (row0 + 64 <= BN) {
    const float4* src4 = (const float4*)(probs + (size_t)row0 * NCLS);
    float4 v[21];
#pragma unroll
    for (int it = 0; it < 21; ++it) {
      const int idx = it * 64 + lane;
      v[it] = src4[idx < NV4 ? idx : 0];   // all 21 loads issued back-to-back
    }
    float4* dst4 = (float4*)s_p;
#pragma unroll
    for (int it = 0; it < 21; ++it) {
      const int idx = it * 64 + lane;
      if (idx < NV4) dst4[idx] = v[it];
    }
  } else {
    const int tot = (BN - row0) * NCLS;
    const float* src = probs + (size_t)row0 * NCLS;
    for (int i = lane; i < tot; i += 64) s_p[i] = src[i];
  }
  __syncthreads();

  const int row = row0 + lane;
  if (row >= BN) return;
  const float* pr = s_p + lane * NCLS;  // stride-81: 17*lane bank perm, clean
  float maxv = pr[0];
  int arg = 0;
#pragma unroll
  for (int k = 1; k < NCLS; ++k) {
    const float v = pr[k];
    if (v > maxv) { maxv = v; arg = k; }  // strict > keeps lowest idx (jnp.argmax)
  }
  const bool cand = (maxv > 0.7f) && (arg != 0);
  cand_cls[row] = cand ? arg : -1;
  cand_sc[row] = maxv;
  if (cand) {
    const float4 r4 = *(const float4*)(rois + (size_t)row * 4);
    const float h = r4.z - r4.x, w = r4.w - r4.y;
    const float cy = r4.x + 0.5f * h, cx = r4.y + 0.5f * w;
    const float4 d4 = *(const float4*)(deltas + (size_t)row * (NCLS * 4) + arg * 4);
    const float bh  = expf(d4.z * 0.2f) * h;
    const float bw  = expf(d4.w * 0.2f) * w;
    const float bcy = d4.x * 0.1f * h + cy;
    const float bcx = d4.y * 0.1f * w + cx;
    const float y1 = bcy - 0.5f * bh, x1 = bcx - 0.5f * bw;
    cand_box[row] = make_float4(y1, x1, y1 + bh, x1 + bw);  // unclipped for NMS
  }
}

// ---------------------------------------------------------------------------
// K2: one wave per (b,l). Reg-prefetch coalesced class scan, LDS compaction
// (row-ascending), one cooperative gather, exact greedy NMS (== reference's
// 200-step scan), then ONE atomicAdd appends this class's selections to the
// per-batch flat list. Output order is nondeterministic but the sort key in
// K3 is a strict total order -> deterministic final output.
// ---------------------------------------------------------------------------
template <int NT>
__global__ __launch_bounds__(64) void nms_per_class(
    const int* __restrict__ cand_cls, const float* __restrict__ cand_sc,
    const float4* __restrict__ cand_box, float* __restrict__ flat,
    int* __restrict__ counters) {
  constexpr int ITERS = (NT + 63) / 64;
  const int bl = blockIdx.x;
  const int b  = bl / NCLS;
  const int l  = bl % NCLS;
  const int lane = threadIdx.x;
  if (l == 0) return;   // background never passes the threshold

  __shared__ int   s_idx[NMAX];
  __shared__ float s_score[NMAX];
  __shared__ float s_box[NMAX][4];
  __shared__ int   s_sel[KMAX];
  __shared__ float s_sel_score[KMAX];
  __shared__ int   s_base;

  int cv[ITERS];
#pragma unroll
  for (int it = 0; it < ITERS; ++it) {
    const int n = it * 64 + lane;
    cv[it] = (n < NT) ? cand_cls[b * NT + n] : -1;
  }
  int m = 0;
#pragma unroll
  for (int it = 0; it < ITERS; ++it) {
    const bool cand = (cv[it] == l);
    const unsigned long long mask = __ballot(cand);
    if (cand)
      s_idx[m + __popcll(mask & ((1ull << lane) - 1ull))] = it * 64 + lane;
    m += __popcll(mask);
  }
  if (m == 0) return;
  __syncthreads();

  for (int i = lane; i < m; i += 64) {
    const int n = s_idx[i];
    s_score[i] = cand_sc[b * NT + n];
    const float4 bx = cand_box[b * NT + n];
    s_box[i][0] = bx.x; s_box[i][1] = bx.y;
    s_box[i][2] = bx.z; s_box[i][3] = bx.w;
  }
  __syncthreads();

  int kept = 0;
  while (kept < KMAX) {
    float best = -1.0f;
    int bi = -1;
    for (int i = lane; i < m; i += 64) {
      const float s = s_score[i];
      if (s > best) { best = s; bi = i; }   // strided ascending: first max kept
    }
    for (int off = 32; off > 0; off >>= 1) {
      const float ob = __shfl_down(best, off);
      const int   oi = __shfl_down(bi, off);
      if (ob > best || (ob == best && (unsigned)oi < (unsigned)bi)) {
        best = ob; bi = oi;
      }
    }
    best = __shfl(best, 0);
    bi   = __shfl(bi, 0);
    if (best <= 0.7f) break;   // all remaining picks invalid

    if (lane == 0) { s_sel[kept] = bi; s_sel_score[kept] = best; }

    const float by1 = s_box[bi][0], bx1 = s_box[bi][1];
    const float by2 = s_box[bi][2], bx2 = s_box[bi][3];
    const float a1 = (by2 - by1) * (bx2 - bx1);
    for (int i = lane; i < m; i += 64) {
      const float ty1 = s_box[i][0], tx1 = s_box[i][1];
      const float ty2 = s_box[i][2], tx2 = s_box[i][3];
      const float yy1 = fmaxf(by1, ty1), xx1 = fmaxf(bx1, tx1);
      const float yy2 = fminf(by2, ty2), xx2 = fminf(bx2, tx2);
      const float inter = fmaxf(yy2 - yy1, 0.0f) * fmaxf(xx2 - xx1, 0.0f);
      const float a2  = (ty2 - ty1) * (tx2 - tx1);
      const float uni = a1 + a2 - inter;
      const float iou = (uni > 0.0f) ? (inter / uni) : 0.0f;
      if (iou > 0.5f) s_score[i] = -INFINITY;   // self iou=1 -> suppressed
    }
    kept++;
    __syncthreads();
  }
  __syncthreads();

  if (lane == 0) s_base = (kept > 0) ? atomicAdd(&counters[b], kept) : 0;
  __syncthreads();
  const int base = s_base;
  for (int i = lane; i < kept; i += 64) {
    const int slot = base + i;
    if (slot < FCAP) {
      float* e = flat + ((size_t)b * FCAP + slot) * 8;
      const int ci = s_sel[i];
      e[0] = s_sel_score[i];
      ((int*)e)[1] = l * KMAX + i;   // flat index: top_k tie-break key
      e[2] = fminf(fmaxf(s_box[ci][0], 0.0f), 1.0f);
      e[3] = fminf(fmaxf(s_box[ci][1], 0.0f), 1.0f);
      e[4] = fminf(fmaxf(s_box[ci][2], 0.0f), 1.0f);
      e[5] = fminf(fmaxf(s_box[ci][3], 0.0f), 1.0f);
    }
  }
}

// Runtime-N fallback (unused for N=1500): NMS over global cand arrays with
// class predicate — slow but correct for any N.
__global__ __launch_bounds__(64) void nms_per_class_rt(
    const int* __restrict__ cand_cls, const float* __restrict__ cand_sc,
    const float4* __restrict__ cand_box, float* __restrict__ flat,
    int* __restrict__ counters, int N) {
  const int bl = blockIdx.x;
  const int b  = bl / NCLS;
  const int l  = bl % NCLS;
  const int lane = threadIdx.x;
  if (l == 0) return;
  __shared__ float s_sc2[8192 > NMAX ? 8192 : NMAX];  // mutable scores (cap 8192)
  __shared__ int s_selrow[KMAX];
  __shared__ float s_selsc[KMAX];
  __shared__ int s_base;
  const int cap = 8192;
  for (int n = lane; n < N && n < cap; n += 64)
    s_sc2[n] = (cand_cls[b * N + n] == l) ? cand_sc[b * N + n] : -INFINITY;
  __syncthreads();
  const int nn = (N < cap) ? N : cap;
  int kept = 0;
  while (kept < KMAX) {
    float best = -1.0f; int bi = -1;
    for (int i = lane; i < nn; i += 64) {
      const float s = s_sc2[i];
      if (s > best) { best = s; bi = i; }
    }
    for (int off = 32; off > 0; off >>= 1) {
      const float ob = __shfl_down(best, off);
      const int   oi = __shfl_down(bi, off);
      if (ob > best || (ob == best && (unsigned)oi < (unsigned)bi)) { best = ob; bi = oi; }
    }
    best = __shfl(best, 0); bi = __shfl(bi, 0);
    if (best <= 0.7f) break;
    if (lane == 0) { s_selrow[kept] = bi; s_selsc[kept] = best; }
    const float4 bb = cand_box[b * N + bi];
    const float a1 = (bb.z - bb.x) * (bb.w - bb.y);
    for (int i = lane; i < nn; i += 64) {
      if (s_sc2[i] != -INFINITY) {
        const float4 tb = cand_box[b * N + i];
        const float yy1 = fmaxf(bb.x, tb.x), xx1 = fmaxf(bb.y, tb.y);
        const float yy2 = fminf(bb.z, tb.z), xx2 = fminf(bb.w, tb.w);
        const float inter = fmaxf(yy2 - yy1, 0.0f) * fmaxf(xx2 - xx1, 0.0f);
        const float a2  = (tb.z - tb.x) * (tb.w - tb.y);
        const float uni = a1 + a2 - inter;
        const float iou = (uni > 0.0f) ? (inter / uni) : 0.0f;
        if (iou > 0.5f) s_sc2[i] = -INFINITY;
      }
    }
    kept++;
    __syncthreads();
  }
  __syncthreads();
  if (lane == 0) s_base = (kept > 0) ? atomicAdd(&counters[b], kept) : 0;
  __syncthreads();
  for (int i = lane; i < kept; i += 64) {
    const int slot = s_base + i;
    if (slot < FCAP) {
      float* e = flat + ((size_t)b * FCAP + slot) * 8;
      const float4 bb = cand_box[b * N + s_selrow[i]];
      e[0] = s_selsc[i];
      ((int*)e)[1] = l * KMAX + i;
      e[2] = fminf(fmaxf(bb.x, 0.0f), 1.0f);
      e[3] = fminf(fmaxf(bb.y, 0.0f), 1.0f);
      e[4] = fminf(fmaxf(bb.z, 0.0f), 1.0f);
      e[5] = fminf(fmaxf(bb.w, 0.0f), 1.0f);
    }
  }
}

// ---------------------------------------------------------------------------
// K3: 4 blocks x 64 threads (ONE wave -> barriers are near-free). Read the
// per-batch flat list (c entries, usually ~30), bitonic sort on
// (score desc, flat idx asc), emit top-200 with zero fill.
// ---------------------------------------------------------------------------
__global__ __launch_bounds__(64) void topk_per_batch(
    const float* __restrict__ flat,     // [B][FCAP][8]
    const int* __restrict__ counters,   // [8]
    float* __restrict__ out, int B) {
  const int b = blockIdx.x;
  const int lane = threadIdx.x;

  __shared__ unsigned long long s_key[FCAP];
  __shared__ short s_pay[FCAP];

  int c = counters[b];
  if (c > FCAP) c = FCAP;
  int M = 64;
  while (M < c) M <<= 1;

  for (int i = lane; i < M; i += 64) {
    unsigned long long k = 0ull;
    if (i < c) {
      const float* e = flat + ((size_t)b * FCAP + i) * 8;
      const unsigned sb = __float_as_uint(e[0]);          // score > 0.7 > 0
      const unsigned fi = (unsigned)(((const int*)e)[1]);
      k = ((unsigned long long)sb << 32) |
          (unsigned long long)(0xFFFFFFFFu - fi);
    }
    s_key[i] = k;
    s_pay[i] = (short)i;
  }
  __syncthreads();

  for (int kk = 2; kk <= M; kk <<= 1) {
    for (int j2 = kk >> 1; j2 > 0; j2 >>= 1) {
      for (int i = lane; i < M; i += 64) {
        const int ixj = i ^ j2;
        if (ixj > i) {
          const bool up = ((i & kk) == 0);  // descending overall
          const unsigned long long a = s_key[i], bb = s_key[ixj];
          const bool sw = up ? (a < bb) : (a > bb);
          if (sw) {
            s_key[i] = bb; s_key[ixj] = a;
            const short t = s_pay[i]; s_pay[i] = s_pay[ixj]; s_pay[ixj] = t;
          }
        }
      }
      __syncthreads();
    }
  }

  const size_t boxes_sz = (size_t)B * KMAX * 4;
  for (int t = lane; t < KMAX; t += 64) {
    float sc = 0.0f, lb = 0.0f, b0 = 0.0f, b1 = 0.0f, b2 = 0.0f, b3 = 0.0f;
    if (t < c) {
      const unsigned long long k = s_key[t];
      sc = __uint_as_float((unsigned)(k >> 32));
      const unsigned fi = 0xFFFFFFFFu - (unsigned)(k & 0xFFFFFFFFull);
      lb = (float)(fi / KMAX);
      const float* e = flat + ((size_t)b * FCAP + s_pay[t]) * 8;
      b0 = e[2]; b1 = e[3]; b2 = e[4]; b3 = e[5];
    }
    float* ob = out + (size_t)b * (KMAX * 4) + (size_t)t * 4;
    ob[0] = b0; ob[1] = b1; ob[2] = b2; ob[3] = b3;
    out[boxes_sz + (size_t)b * KMAX + t] = lb;
    out[boxes_sz + (size_t)B * KMAX + (size_t)b * KMAX + t] = sc;
  }
}

// Runtime-N K1 fallback
__global__ __launch_bounds__(64) void row_scan_rt(
    const float* __restrict__ rois, const float* __restrict__ deltas,
    const float* __restrict__ probs, int* __restrict__ cand_cls,
    float* __restrict__ cand_sc, float4* __restrict__ cand_box,
    int* __restrict__ counters, int BN) {
  __shared__ float s_p[64 * NCLS];
  const int lane = threadIdx.x;
  const int row0 = blockIdx.x * 64;
  if (blockIdx.x == 0 && lane < 8) counters[lane] = 0;
  const int tot = (min(64, BN - row0)) * NCLS;
  const float* src = probs + (size_t)row0 * NCLS;
  for (int i = lane; i < tot; i += 64) s_p[i] = src[i];
  __syncthreads();
  const int row = row0 + lane;
  if (row >= BN) return;
  const float* pr = s_p + lane * NCLS;
  float maxv = pr[0];
  int arg = 0;
  for (int k = 1; k < NCLS; ++k) {
    const float v = pr[k];
    if (v > maxv) { maxv = v; arg = k; }
  }
  const bool cand = (maxv > 0.7f) && (arg != 0);
  cand_cls[row] = cand ? arg : -1;
  cand_sc[row] = maxv;
  if (cand) {
    const float4 r4 = *(const float4*)(rois + (size_t)row * 4);
    const float h = r4.z - r4.x, w = r4.w - r4.y;
    const float cy = r4.x + 0.5f * h, cx = r4.y + 0.5f * w;
    const float4 d4 = *(const float4*)(deltas + (size_t)row * (NCLS * 4) + arg * 4);
    const float bh  = expf(d4.z * 0.2f) * h;
    const float bw  = expf(d4.w * 0.2f) * w;
    const float bcy = d4.x * 0.1f * h + cy;
    const float bcx = d4.y * 0.1f * w + cx;
    const float y1 = bcy - 0.5f * bh, x1 = bcx - 0.5f * bw;
    cand_box[row] = make_float4(y1, x1, y1 + bh, x1 + bw);
  }
}

// ---------------------------------------------------------------------------
extern "C" void kernel_launch(void* const* d_in, const int* in_sizes, int n_in,
                              void* d_out, int out_size, void* d_ws, size_t ws_size,
                              hipStream_t stream) {
  const float* rois   = (const float*)d_in[0];
  const float* deltas = (const float*)d_in[1];
  const float* probs  = (const float*)d_in[2];
  float* out = (float*)d_out;

  const int B = 4;
  const int N = in_sizes[0] / (B * 4);   // 1500
  const int BN = B * N;

  char* ws = (char*)d_ws;
  int*    counters = (int*)ws;
  float*  flat     = (float*)(ws + 256);
  int*    cand_cls = (int*)(ws + 262400);
  float*  cand_sc  = (float*)(ws + 262400 + 64 * (size_t)N);
  float4* cand_box = (float4*)(ws + 262400 + 128 * (size_t)N);

  if (N == 1500) {
    hipLaunchKernelGGL((row_scan<1500>), dim3((BN + 63) / 64), dim3(64), 0,
                       stream, rois, deltas, probs, cand_cls, cand_sc,
                       cand_box, counters, BN);
    hipLaunchKernelGGL((nms_per_class<1500>), dim3(B * NCLS), dim3(64), 0,
                       stream, cand_cls, cand_sc, cand_box, flat, counters);
  } else {
    hipLaunchKernelGGL(row_scan_rt, dim3((BN + 63) / 64), dim3(64), 0, stream,
                       rois, deltas, probs, cand_cls, cand_sc, cand_box,
                       counters, BN);
    hipLaunchKernelGGL(nms_per_class_rt, dim3(B * NCLS), dim3(64), 0, stream,
                       cand_cls, cand_sc, cand_box, flat, counters, N);
  }
  hipLaunchKernelGGL(topk_per_batch, dim3(B), dim3(64), 0, stream,
                     flat, counters, out, B);
}

// Round 8
// 51.559 us; speedup vs baseline: 1.8547x; 1.6874x over previous
//
#include <hip/hip_runtime.h>
#include <math.h>

#define NCLS 81
#define KMAX 200
#define NMAX 1536      // max candidates per (b,l) stageable in LDS (>= N=1500)
#define SORT_CAP 2048  // >= max total detections per batch (<= N)

// ws layout (all offsets 16B-aligned):
//   counts   [B*NCLS] int      @ 0        (4 KB region)
//   entries  [B*NCLS][KMAX][8] @ 4096     (2 073 600 B)
//   cand_cls [B*N] int         @ 2077696
//   cand_sc  [B*N] float       @ +24064
//   cand_box [B*N] float4      @ +24064

// ---------------------------------------------------------------------------
// K1: one wave per 64 rows. Coalesced-stage 64 probs rows into LDS, per-lane
// row max/argmax (prob>0.7 => unique strict argmax => candidate class), decode
// the candidate's box, write dense candidate arrays. No atomics.
// ---------------------------------------------------------------------------
__global__ __launch_bounds__(64) void row_scan(
    const float* __restrict__ rois,     // [B*N,4]
    const float* __restrict__ deltas,   // [B*N,81*4]
    const float* __restrict__ probs,    // [B*N,81]
    int* __restrict__ cand_cls,         // [B*N]
    float* __restrict__ cand_sc,        // [B*N]
    float4* __restrict__ cand_box,      // [B*N]
    int BN) {
  __shared__ float s_p[64 * NCLS];
  const int lane = threadIdx.x;
  const int row0 = blockIdx.x * 64;
  const int nrows = min(64, BN - row0);

  const float* src = probs + (size_t)row0 * NCLS;
  const int tot = nrows * NCLS;
  for (int i = lane; i < tot; i += 64) s_p[i] = src[i];
  __syncthreads();
  if (lane >= nrows) return;

  const int row = row0 + lane;
  const float* pr = s_p + lane * NCLS;   // stride-81 across lanes: 2-way alias, free
  float maxv = pr[0];
  int arg = 0;
  for (int k = 1; k < NCLS; ++k) {
    const float v = pr[k];
    if (v > maxv) { maxv = v; arg = k; }   // strict > keeps lowest index (jnp.argmax)
  }
  const bool cand = (maxv > 0.7f) && (arg != 0);
  cand_cls[row] = cand ? arg : -1;
  cand_sc[row] = maxv;
  if (cand) {
    const float* r = rois + (size_t)row * 4;
    const float ay1 = r[0], ax1 = r[1], ay2 = r[2], ax2 = r[3];
    const float h = ay2 - ay1, w = ax2 - ax1;
    const float cy = ay1 + 0.5f * h, cx = ax1 + 0.5f * w;
    const float* d = deltas + (size_t)row * (NCLS * 4) + arg * 4;
    const float bh  = expf(d[2] * 0.2f) * h;
    const float bw  = expf(d[3] * 0.2f) * w;
    const float bcy = d[0] * 0.1f * h + cy;
    const float bcx = d[1] * 0.1f * w + cx;
    const float y1 = bcy - 0.5f * bh, x1 = bcx - 0.5f * bw;
    cand_box[row] = make_float4(y1, x1, y1 + bh, x1 + bw);  // unclipped for NMS
  }
}

// ---------------------------------------------------------------------------
// K2: one wave per (b,l). Compact this class's candidates (coalesced int scan
// of cand_cls, n-ascending order preserved), exact greedy NMS (equivalent to
// the reference's 200-step scan), write per-class entries + count. No atomics.
// ---------------------------------------------------------------------------
__global__ __launch_bounds__(64) void nms_per_class(
    const int* __restrict__ cand_cls,   // [B*N]
    const float* __restrict__ cand_sc,  // [B*N]
    const float4* __restrict__ cand_box,// [B*N]
    float* __restrict__ entries,        // [B*NCLS][KMAX][8]
    int* __restrict__ counts,           // [B*NCLS]
    int N) {
  const int bl = blockIdx.x;
  const int b  = bl / NCLS;
  const int l  = bl % NCLS;
  const int lane = threadIdx.x;
  if (l == 0) {                 // background never passes the threshold
    if (lane == 0) counts[bl] = 0;
    return;
  }

  __shared__ float s_score[NMAX];
  __shared__ float s_box[NMAX][4];
  __shared__ int   s_sel[KMAX];
  __shared__ float s_sel_score[KMAX];

  // ---- candidate compaction (coalesced; n-ascending order preserved) ----
  int m = 0;
  for (int n0 = 0; n0 < N; n0 += 64) {
    const int n = n0 + lane;
    const int c = (n < N) ? cand_cls[b * N + n] : -1;
    const bool cand = (c == l);
    const unsigned long long mask = __ballot(cand);
    if (cand) {
      const int idx = m + __popcll(mask & ((1ull << lane) - 1ull));
      const float4 bx = cand_box[b * N + n];
      s_score[idx]  = cand_sc[b * N + n];
      s_box[idx][0] = bx.x;
      s_box[idx][1] = bx.y;
      s_box[idx][2] = bx.z;
      s_box[idx][3] = bx.w;
    }
    m += __popcll(mask);
  }
  __syncthreads();

  // ---- greedy NMS ----
  int kept = 0;
  while (kept < KMAX) {
    float best = -1.0f;
    int bi = -1;
    for (int i = lane; i < m; i += 64) {
      const float s = s_score[i];
      if (s > best) { best = s; bi = i; }   // strided ascending: first max kept
    }
    for (int off = 32; off > 0; off >>= 1) {
      const float ob = __shfl_down(best, off);
      const int   oi = __shfl_down(bi, off);
      if (ob > best || (ob == best && (unsigned)oi < (unsigned)bi)) {
        best = ob; bi = oi;
      }
    }
    best = __shfl(best, 0);
    bi   = __shfl(bi, 0);
    if (best <= 0.7f) break;   // all remaining picks invalid

    if (lane == 0) { s_sel[kept] = bi; s_sel_score[kept] = best; }

    const float by1 = s_box[bi][0], bx1 = s_box[bi][1];
    const float by2 = s_box[bi][2], bx2 = s_box[bi][3];
    const float a1 = (by2 - by1) * (bx2 - bx1);
    for (int i = lane; i < m; i += 64) {
      const float ty1 = s_box[i][0], tx1 = s_box[i][1];
      const float ty2 = s_box[i][2], tx2 = s_box[i][3];
      const float yy1 = fmaxf(by1, ty1), xx1 = fmaxf(bx1, tx1);
      const float yy2 = fminf(by2, ty2), xx2 = fminf(bx2, tx2);
      const float inter = fmaxf(yy2 - yy1, 0.0f) * fmaxf(xx2 - xx1, 0.0f);
      const float a2  = (ty2 - ty1) * (tx2 - tx1);
      const float uni = a1 + a2 - inter;
      const float iou = (uni > 0.0f) ? (inter / uni) : 0.0f;
      if (iou > 0.5f) s_score[i] = -INFINITY;   // self iou=1 -> suppressed
    }
    kept++;
    __syncthreads();
  }
  __syncthreads();

  // ---- write per-class results ----
  if (lane == 0) counts[bl] = kept;
  float* ebase = entries + (size_t)bl * KMAX * 8;
  for (int i = lane; i < kept; i += 64) {
    float* e = ebase + (size_t)i * 8;
    const int ci = s_sel[i];
    e[0] = s_sel_score[i];
    e[1] = fminf(fmaxf(s_box[ci][0], 0.0f), 1.0f);
    e[2] = fminf(fmaxf(s_box[ci][1], 0.0f), 1.0f);
    e[3] = fminf(fmaxf(s_box[ci][2], 0.0f), 1.0f);
    e[4] = fminf(fmaxf(s_box[ci][3], 0.0f), 1.0f);
  }
}

// ---------------------------------------------------------------------------
// K3: one block per batch. Prefix-sum the 81 counts, gather 64-bit keys
// (score desc, flat index asc — low bits ARE the payload), bitonic sort only
// next_pow2(total) slots, emit top-200.
// ---------------------------------------------------------------------------
__global__ __launch_bounds__(1024) void topk_per_batch(
    const float* __restrict__ entries,  // [B*NCLS][KMAX][8]
    const int* __restrict__ counts,     // [B*NCLS]
    float* __restrict__ out, int B) {
  const int b   = blockIdx.x;
  const int tid = threadIdx.x;

  __shared__ int s_cnt[NCLS];
  __shared__ int s_off[NCLS];
  __shared__ int s_total, s_M;
  __shared__ unsigned long long s_key[SORT_CAP];

  if (tid < NCLS) s_cnt[tid] = counts[b * NCLS + tid];
  __syncthreads();
  if (tid == 0) {
    int acc = 0;
    for (int l = 0; l < NCLS; ++l) { s_off[l] = acc; acc += s_cnt[l]; }
    s_total = acc;
    int M = 64;
    while (M < acc) M <<= 1;
    s_M = M;
  }
  __syncthreads();
  const int c = s_total;
  const int M = s_M;     // c <= N <= SORT_CAP guaranteed

  for (int i = tid; i < M; i += 1024) s_key[i] = 0ull;
  __syncthreads();
  for (int j = tid; j < NCLS * KMAX; j += 1024) {
    const int l = j / KMAX, k = j - l * KMAX;
    if (k < s_cnt[l]) {
      const float sc = entries[((size_t)(b * NCLS + l) * KMAX + k) * 8];
      const unsigned sb = __float_as_uint(sc);           // score > 0.7 > 0
      s_key[s_off[l] + k] =
          ((unsigned long long)sb << 32) |
          (unsigned long long)(0xFFFFFFFFu - (unsigned)(l * KMAX + k));
    }
  }
  __syncthreads();

  for (int kk = 2; kk <= M; kk <<= 1) {
    for (int j2 = kk >> 1; j2 > 0; j2 >>= 1) {
      for (int i = tid; i < M; i += 1024) {
        const int ixj = i ^ j2;
        if (ixj > i) {
          const bool up = ((i & kk) == 0);  // descending overall
          const unsigned long long a = s_key[i], bb = s_key[ixj];
          const bool sw = up ? (a < bb) : (a > bb);
          if (sw) { s_key[i] = bb; s_key[ixj] = a; }
        }
      }
      __syncthreads();
    }
  }

  if (tid < KMAX) {
    float sc = 0.0f, lb = 0.0f, b0 = 0.0f, b1 = 0.0f, b2 = 0.0f, b3 = 0.0f;
    if (tid < c) {
      const unsigned long long k = s_key[tid];
      const unsigned fi = 0xFFFFFFFFu - (unsigned)(k & 0xFFFFFFFFull);
      const int l = fi / KMAX, kk2 = fi - l * KMAX;
      const float* e = entries + ((size_t)(b * NCLS + l) * KMAX + kk2) * 8;
      sc = e[0];
      lb = (float)l;
      b0 = e[1]; b1 = e[2]; b2 = e[3]; b3 = e[4];
    }
    float* ob = out + (size_t)b * (KMAX * 4) + (size_t)tid * 4;
    ob[0] = b0; ob[1] = b1; ob[2] = b2; ob[3] = b3;
    const size_t boxes_sz = (size_t)B * KMAX * 4;
    out[boxes_sz + (size_t)b * KMAX + tid] = lb;
    out[boxes_sz + (size_t)B * KMAX + (size_t)b * KMAX + tid] = sc;
  }
}

// ---------------------------------------------------------------------------
extern "C" void kernel_launch(void* const* d_in, const int* in_sizes, int n_in,
                              void* d_out, int out_size, void* d_ws, size_t ws_size,
                              hipStream_t stream) {
  const float* rois   = (const float*)d_in[0];
  const float* deltas = (const float*)d_in[1];
  const float* probs  = (const float*)d_in[2];
  float* out = (float*)d_out;

  const int B = 4;
  const int N = in_sizes[0] / (B * 4);   // 1500
  const int BN = B * N;

  char* ws = (char*)d_ws;
  int*    counts   = (int*)ws;
  float*  entries  = (float*)(ws + 4096);
  int*    cand_cls = (int*)(ws + 2077696);
  float*  cand_sc  = (float*)(ws + 2077696 + 24064);
  float4* cand_box = (float4*)(ws + 2077696 + 24064 + 24064);

  hipLaunchKernelGGL(row_scan, dim3((BN + 63) / 64), dim3(64), 0, stream,
                     rois, deltas, probs, cand_cls, cand_sc, cand_box, BN);
  hipLaunchKernelGGL(nms_per_class, dim3(B * NCLS), dim3(64), 0, stream,
                     cand_cls, cand_sc, cand_box, entries, counts, N);
  hipLaunchKernelGGL(topk_per_batch, dim3(B), dim3(1024), 0, stream,
                     entries, counts, out, B);
}